// Round 10
// baseline (618.368 us; speedup 1.0000x reference)
//
#include <hip/hip_runtime.h>

#define N_IND 100000
#define N_COM 100000
#define N_TRU 100000
#define NTOT  300000
#define NEDGE 4800000
#define HDIM  64
#define CHUNK 4096
#define NCHUNKS_SC 1172 // ceil(NEDGE/CHUNK)
#define NCB 293   // ceil(NTOT/1024) coarse buckets of 1024 nodes
#define CAP 18432 // fixed bucket capacity = 16384 (mean) + 16 sigma (128)
#define PADW 33   // 32 cols + 1 pad (encoder epilogue)
#define NTILES32 9375 // NTOT / 32 exactly
#define NBLK_ENC1 391 // ceil(100000/256)
#define NBLK_ENC  1173
#define NBLK_MEGA 2345 // 1173 encoder blocks + 1172 scatter blocks
#define NBLK_PREP 1237 // 64 wfrag + 1 ccur + 1172 deg-zero

typedef float v4f __attribute__((ext_vector_type(4)));
typedef unsigned short v4u __attribute__((ext_vector_type(4)));
typedef unsigned short v8u __attribute__((ext_vector_type(8)));
typedef _Float16 v8h __attribute__((ext_vector_type(8)));

static __device__ __forceinline__ float elem4(const float4 v, int j) {
  return j == 0 ? v.x : j == 1 ? v.y : j == 2 ? v.z : v.w;
}

// fp32 <-> fp16 (RTN via v_cvt)
static __device__ __forceinline__ unsigned short f2h(float f) {
  _Float16 h = (_Float16)f;
  return __builtin_bit_cast(unsigned short, h);
}
static __device__ __forceinline__ float h2f(unsigned short u) {
  return (float)__builtin_bit_cast(_Float16, u);
}

// acc += (float)lo_half(pk); acc2 += (float)hi_half(pk) — one v_fma_mix_f32 each.
// Bitwise identical to v_cvt_f32_f16 + v_add_f32 (exact convert, x1.0 exact, one round).
static __device__ __forceinline__ void fmix2(float& alo, float& ahi, unsigned pk) {
  asm("v_fma_mix_f32 %0, %1, 1.0, %0 op_sel:[0,0,0] op_sel_hi:[1,0,0]"
      : "+v"(alo) : "v"(pk));
  asm("v_fma_mix_f32 %0, %1, 1.0, %0 op_sel:[1,0,0] op_sel_hi:[1,0,0]"
      : "+v"(ahi) : "v"(pk));
}

// Coalesced fp16 epilogue for encoder (256 rows, 2 stages of 32 cols).
static __device__ __forceinline__ void store_rows_f16(
    unsigned short* __restrict__ out, float* __restrict__ st, const float* acc,
    int node0, int rows, int tid, bool active) {
#pragma unroll
  for (int stage = 0; stage < 2; ++stage) {
    __syncthreads();
    if (active) {
#pragma unroll
      for (int j = 0; j < 32; ++j) st[tid * PADW + j] = acc[stage * 32 + j];
    }
    __syncthreads();
#pragma unroll
    for (int it = 0; it < 8; ++it) {
      int e = it * 256 + tid;
      int r = e >> 3;
      int c = (e & 7) * 4;
      if (r < rows) {
        v4u o;
        o.x = f2h(st[r * PADW + c + 0]);
        o.y = f2h(st[r * PADW + c + 1]);
        o.z = f2h(st[r * PADW + c + 2]);
        o.w = f2h(st[r * PADW + c + 3]);
        *(v4u*)(out + (size_t)(node0 + r) * HDIM + stage * 32 + c) = o;
      }
    }
  }
}

// ---------------- encoder body: xh[base+n] = fp16(x[n] @ W + b) ----------------
template <int K>
static __device__ void encode_body(
    const float* __restrict__ xin, const float* __restrict__ W,
    const float* __restrict__ b, unsigned short* __restrict__ xhout,
    int n, int base, int blk, float* st) {
  int tid = threadIdx.x;
  int node0 = blk * 256;
  int node = node0 + tid;
  bool active = node < n;
  int rows = min(256, n - node0);
  float acc[HDIM];
  if (active) {
    float4 row[K / 4];
    const float4* xv = (const float4*)(xin + (size_t)node * K);
#pragma unroll
    for (int i = 0; i < K / 4; ++i) row[i] = xv[i];
#pragma unroll
    for (int f = 0; f < HDIM; ++f) acc[f] = b[f];  // uniform -> s_load
#pragma unroll
    for (int k4 = 0; k4 < K / 4; ++k4) {
#pragma unroll
      for (int j = 0; j < 4; ++j) {
        float xs = elem4(row[k4], j);
        int k = k4 * 4 + j;
#pragma unroll
        for (int f = 0; f < HDIM; ++f) acc[f] += xs * W[k * HDIM + f];
      }
    }
  }
  store_rows_f16(xhout + (size_t)base * HDIM, st, acc, node0, rows, tid, active);
}

// ---------------- scatter body: LDS-staged local sort, coalesced run writes ----------
// CHUNK=4096 (LDS 28.9 KB -> union 33.8 KB -> 4 blocks/CU). Also accumulates global
// per-node degrees (fire-and-forget atomics, hidden under the latency-bound phase) so
// sort_coarse can skip its histogram pass entirely.
static __device__ void scatter_body(
    const int* __restrict__ src, const int* __restrict__ dst,
    int* __restrict__ ccur, unsigned* __restrict__ packed, int* __restrict__ deg,
    int e, int blk, char* smem) {
  int* h = (int*)smem;                       // NCB counts / rank counters
  int* gofs = h + NCB;                       // NCB global-offset deltas
  int* sv = gofs + NCB;                      // 512-wide scan buffer
  unsigned* vals = (unsigned*)(sv + 512);    // CHUNK sorted values
  unsigned short* sbid = (unsigned short*)(vals + CHUNK);  // CHUNK bucket ids
  int tid = threadIdx.x;
  int start = blk * CHUNK;
  int len = min(CHUNK, e - start);

  for (int i = tid; i < NCB; i += 256) h[i] = 0;
  __syncthreads();

  // Phase A: histogram (+ global deg accumulate); keep dst in registers for phase C.
  int dreg[CHUNK / 256];
#pragma unroll
  for (int k = 0; k < CHUNK / 256; ++k) {
    int i = k * 256 + tid;
    dreg[k] = (i < len) ? dst[start + i] : -1;
    if (i < len) {
      atomicAdd(&h[dreg[k] >> 10], 1);
      atomicAdd(&deg[dreg[k]], 1);   // no return use -> fire-and-forget
    }
  }
  __syncthreads();

  // Phase B: 512-wide Hillis-Steele scan (256 threads x 2 slots), reserve runs.
  sv[tid] = (tid < NCB) ? h[tid] : 0;
  sv[tid + 256] = (tid + 256 < NCB) ? h[tid + 256] : 0;
  __syncthreads();
  for (int o = 1; o < 512; o <<= 1) {
    int y0 = (tid >= o) ? sv[tid - o] : 0;
    int y1 = sv[tid + 256 - o];  // tid+256 >= o always (o <= 256)
    __syncthreads();
    sv[tid] += y0;
    sv[tid + 256] += y1;
    __syncthreads();
  }
  for (int b = tid; b < NCB; b += 256) {
    int c = h[b];
    int lo = (b == 0) ? 0 : sv[b - 1];
    int gb = (c > 0) ? atomicAdd(&ccur[b], c) : 0;  // reserve contiguous run
    gofs[b] = gb - lo;
    h[b] = lo;  // reuse as rank counter
  }
  __syncthreads();

  // Phase C: scatter into LDS in locally-sorted order.
#pragma unroll
  for (int k = 0; k < CHUNK / 256; ++k) {
    int i = k * 256 + tid;
    if (i < len) {
      int d = dreg[k];
      int s = src[start + i];
      int b = d >> 10;
      int slot = atomicAdd(&h[b], 1);
      vals[slot] = ((unsigned)s << 10) | (unsigned)(d & 1023);
      sbid[slot] = (unsigned short)b;
    }
  }
  __syncthreads();

  // Phase D: coalesced sweep; dense sequential within each bucket run.
  for (int i = tid; i < len; i += 256) {
    int b = sbid[i];
    packed[gofs[b] + i] = vals[i];
  }
}

// ---------------- MEGA front: encoders + coarse scatter in ONE dispatch ----------------
// Blocks 0..1172: per-type encoders. Blocks 1173..2344: scatter chunks. LDS union
// 33792 B -> 4 blocks/CU (round-8 at 53.5 KB sat at 2 blocks / 25% occupancy — the
// co-residency this fusion needs was missing; this round restores it).
__global__ __launch_bounds__(256, 4) void mega_front_kernel(
    const float* __restrict__ x_ind, const float* __restrict__ W_ind, const float* __restrict__ b_ind,
    const float* __restrict__ x_com, const float* __restrict__ W_com, const float* __restrict__ b_com,
    const float* __restrict__ x_tru, const float* __restrict__ W_tru, const float* __restrict__ b_tru,
    unsigned short* __restrict__ xh0,
    const int* __restrict__ src, const int* __restrict__ dst,
    int* __restrict__ ccur, unsigned* __restrict__ packed, int* __restrict__ deg) {
  __shared__ __align__(16) char smem[33792];
  int bid = blockIdx.x;
  if (bid < NBLK_ENC1) {
    encode_body<32>(x_ind, W_ind, b_ind, xh0, N_IND, 0, bid, (float*)smem);
  } else if (bid < 2 * NBLK_ENC1) {
    encode_body<48>(x_com, W_com, b_com, xh0, N_COM, N_IND, bid - NBLK_ENC1, (float*)smem);
  } else if (bid < NBLK_ENC) {
    encode_body<24>(x_tru, W_tru, b_tru, xh0, N_TRU, N_IND + N_COM, bid - 2 * NBLK_ENC1,
                    (float*)smem);
  } else {
    scatter_body(src, dst, ccur, packed, deg, NEDGE, bid - NBLK_ENC, smem);
  }
}

// ---------------- prep: weight swizzle + ccur init + deg zero (all parallel) --------
__global__ __launch_bounds__(256) void prep_weights_kernel(
    const float* __restrict__ W1l, const float* __restrict__ W1r,
    const float* __restrict__ W2l, const float* __restrict__ W2r,
    unsigned short* __restrict__ out, int* __restrict__ ccur, int* __restrict__ deg) {
  int bid = blockIdx.x;
  int tid = threadIdx.x;
  if (bid < 64) {
    int idx = bid * 256 + tid;   // 0..16383
    int m = idx >> 12;
    int id2 = idx & 4095;
    const float* W = (m == 0) ? W1l : (m == 1) ? W1r : (m == 2) ? W2l : W2r;
    int j = id2 & 7;
    int l = (id2 >> 3) & 63;
    int ts = id2 >> 9;
    int t = ts >> 1, s = ts & 1;
    int k = s * 32 + (l >> 4) * 8 + j;
    int n = t * 16 + (l & 15);
    out[m * 4096 + id2] = f2h(W[k * HDIM + n]);
  } else if (bid == 64) {
    for (int b = tid; b < NCB; b += 256) ccur[b] = b * CAP;
  } else {
    int n = (bid - 65) * 256 + tid;
    if (n < NTOT) deg[n] = 0;
  }
}

// ---------------- per-coarse-bucket rank scatter -> node-grouped CSR ----------------
// Histogram pass eliminated: deg comes from the scatter's global atomics. One scan +
// one rank-scatter pass over packed. Resulting eidx is bit-identical to the two-pass
// version (same cur start values, same iteration order).
__global__ __launch_bounds__(1024) void sort_coarse_kernel(
    const unsigned* __restrict__ packed, const int* __restrict__ ccur,
    const int* __restrict__ deg, int* __restrict__ eidx, int* __restrict__ nodeoff) {
  __shared__ int cur[1024];
  __shared__ int sv[1024];
  int cb = blockIdx.x;
  int tid = threadIdx.x;
  int node = (cb << 10) + tid;
  int base = cb * CAP;
  int c = (node < NTOT) ? deg[node] : 0;
  sv[tid] = c;
  __syncthreads();
  for (int o = 1; o < 1024; o <<= 1) {
    int y = (tid >= o) ? sv[tid - o] : 0;
    __syncthreads();
    sv[tid] += y;
    __syncthreads();
  }
  int ex = sv[tid] - c;   // exclusive prefix
  cur[tid] = ex;
  if (node < NTOT) nodeoff[node] = base + ex;
  __syncthreads();
  int cnt = ccur[cb] - base;
  for (int i = tid; i < cnt; i += 1024) {
    unsigned pr = packed[base + i];
    int dl = (int)(pr & 1023u);
    int r = atomicAdd(&cur[dl], 1);
    eidx[base + r] = (int)(pr >> 10);  // 72 KB region exclusive to this block
  }
}

// ---------------- fused: aggregate -> LDS mean -> MFMA combine -> output ----------------
// Block = 256 threads = 32-node tile; 8 lanes/node x uint4 (16 B/lane, 128 B/row).
// At structural floor: FETCH 304 MB = compulsory 8-XCD table fetch; 2.85 TB/s = HBM
// random-128B service rate; occupancy/width levers exhausted (rounds 4,7).
#define SMPAD 72
template <bool LAYER2>
__global__ __launch_bounds__(256, 7) void agg_combine_kernel(
    const unsigned short* __restrict__ xh, const int* __restrict__ off,
    const int* __restrict__ deg, const int* __restrict__ eidx,
    const unsigned short* __restrict__ wfrag,  // this layer's 2 matrices
    const float* __restrict__ bb,
    unsigned short* __restrict__ outh,         // layer1 output (fp16)
    const float* __restrict__ Wc1, const float* __restrict__ bc1,
    const float* __restrict__ Wc2, const float* __restrict__ bc2,
    float* __restrict__ dout) {                // layer2 classifier output
  __shared__ unsigned short smean[32 * SMPAD];
  __shared__ float st[32 * 68 + 8];
  __shared__ float sW1[LAYER2 ? 2048 : 8];
  int tid = threadIdx.x;
  int node0 = blockIdx.x * 32;

  // ---- phase 1: aggregate; 8 lanes/node, uint4 loads (16 B/lane, 128 B/row) ----
  {
    int nit = tid >> 3;        // node in tile (0..31)
    int lane8 = tid & 7;
    int node = node0 + nit;
    int start = off[node];
    int d = deg[node];
    const char* xb = (const char*)xh;
    unsigned rofs = (unsigned)(lane8 << 4);  // byte offset of this lane in a 128 B row
    // 2 accumulation banks of 8 features; edge e -> bank e&1
    float acc[16];
#pragma unroll
    for (int j = 0; j < 16; ++j) acc[j] = 0.f;
    int i = 0;
    for (; i + 8 <= d; i += 8) {
      const int* ep = eidx + start + i;
      int s[8];
#pragma unroll
      for (int k = 0; k < 8; ++k) s[k] = ep[k];
      uint4 v[8];
#pragma unroll
      for (int k = 0; k < 8; ++k)
        v[k] = *(const uint4*)(xb + ((((unsigned)s[k]) << 7) + rofs));
#pragma unroll
      for (int k = 0; k < 8; ++k) {
        float* a = &acc[(k & 1) * 8];
        fmix2(a[0], a[1], v[k].x);
        fmix2(a[2], a[3], v[k].y);
        fmix2(a[4], a[5], v[k].z);
        fmix2(a[6], a[7], v[k].w);
      }
    }
    if (i + 4 <= d) {
      const int* ep = eidx + start + i;
      int s[4];
#pragma unroll
      for (int k = 0; k < 4; ++k) s[k] = ep[k];
      uint4 v[4];
#pragma unroll
      for (int k = 0; k < 4; ++k)
        v[k] = *(const uint4*)(xb + ((((unsigned)s[k]) << 7) + rofs));
#pragma unroll
      for (int k = 0; k < 4; ++k) {
        float* a = &acc[(k & 1) * 8];
        fmix2(a[0], a[1], v[k].x);
        fmix2(a[2], a[3], v[k].y);
        fmix2(a[4], a[5], v[k].z);
        fmix2(a[6], a[7], v[k].w);
      }
      i += 4;
    }
    for (; i < d; ++i) {
      int s = eidx[start + i];
      uint4 v = *(const uint4*)(xb + ((((unsigned)s) << 7) + rofs));
      fmix2(acc[0], acc[1], v.x);
      fmix2(acc[2], acc[3], v.y);
      fmix2(acc[4], acc[5], v.z);
      fmix2(acc[6], acc[7], v.w);
    }
    float inv = 1.0f / (float)(d > 0 ? d : 1);
    v8u o;
#pragma unroll
    for (int j = 0; j < 8; ++j) o[j] = f2h((acc[j] + acc[8 + j]) * inv);
    *(v8u*)&smean[nit * SMPAD + lane8 * 8] = o;  // 16 B store, row base 144 B (16-aligned)
  }
  if (LAYER2) {
    for (int i = tid; i < 2048; i += 256) sW1[i] = Wc1[i];
  }
  __syncthreads();

  // ---- phase 2: combine; 8 tasks (rt 0..1 x cb 0..3), wave wid does tasks wid*2+{0,1} ----
  int wid = tid >> 6;
  int lane = tid & 63;
  int mlo = lane & 15;
  int quad = lane >> 4;
  {
    const v8h* wf = (const v8h*)wfrag;
#pragma unroll
    for (int p = 0; p < 2; ++p) {
      int task = wid * 2 + p;
      int rt = task >> 2, cb = task & 3;
      v8h BL0 = wf[(cb * 2 + 0) * 64 + lane];
      v8h BL1 = wf[(cb * 2 + 1) * 64 + lane];
      v8h BR0 = wf[512 + (cb * 2 + 0) * 64 + lane];
      v8h BR1 = wf[512 + (cb * 2 + 1) * 64 + lane];
      float bias = bb[cb * 16 + mlo];
      int arow = rt * 16 + mlo;
      v8h Am0 = *(const v8h*)&smean[arow * SMPAD + quad * 8];
      v8h Am1 = *(const v8h*)&smean[arow * SMPAD + quad * 8 + 32];
      const _Float16* xrow =
          (const _Float16*)xh + (size_t)(node0 + arow) * HDIM + quad * 8;
      v8h Ax0 = *(const v8h*)(xrow);
      v8h Ax1 = *(const v8h*)(xrow + 32);
      v4f acc = {bias, bias, bias, bias};
      acc = __builtin_amdgcn_mfma_f32_16x16x32_f16(Am0, BL0, acc, 0, 0, 0);
      acc = __builtin_amdgcn_mfma_f32_16x16x32_f16(Am1, BL1, acc, 0, 0, 0);
      acc = __builtin_amdgcn_mfma_f32_16x16x32_f16(Ax0, BR0, acc, 0, 0, 0);
      acc = __builtin_amdgcn_mfma_f32_16x16x32_f16(Ax1, BR1, acc, 0, 0, 0);
#pragma unroll
      for (int r = 0; r < 4; ++r)
        st[(rt * 16 + quad * 4 + r) * 68 + cb * 16 + mlo] = fmaxf(acc[r], 0.f);
    }
  }
  __syncthreads();

  // ---- phase 3: output ----
  if (!LAYER2) {
    // coalesced fp16 store of the 32x64 tile: row = tid>>3, 8 cols per thread
    int r = tid >> 3;
    int c = (tid & 7) * 8;
    const float* ap = &st[r * 68 + c];
    v8u o;
#pragma unroll
    for (int j = 0; j < 8; ++j) o[j] = f2h(ap[j]);
    *(v8u*)(outh + (size_t)(node0 + r) * HDIM + c) = o;
  } else {
    // classifier: 8 threads/node, 4 hidden units each, shfl-tree reduce over 8 lanes
    int nd = tid >> 3;
    int f = (tid & 7) * 4;
    float h0 = bc1[f], h1 = bc1[f + 1], h2 = bc1[f + 2], h3 = bc1[f + 3];
    const float* xr = &st[nd * 68];
#pragma unroll
    for (int k = 0; k < 64; ++k) {
      float xv = xr[k];
      h0 += xv * sW1[k * 32 + f + 0];
      h1 += xv * sW1[k * 32 + f + 1];
      h2 += xv * sW1[k * 32 + f + 2];
      h3 += xv * sW1[k * 32 + f + 3];
    }
    h0 = fmaxf(h0, 0.f); h1 = fmaxf(h1, 0.f);
    h2 = fmaxf(h2, 0.f); h3 = fmaxf(h3, 0.f);
    float o0 = h0 * Wc2[f * 2 + 0] + h1 * Wc2[(f + 1) * 2 + 0] +
               h2 * Wc2[(f + 2) * 2 + 0] + h3 * Wc2[(f + 3) * 2 + 0];
    float o1 = h0 * Wc2[f * 2 + 1] + h1 * Wc2[(f + 1) * 2 + 1] +
               h2 * Wc2[(f + 2) * 2 + 1] + h3 * Wc2[(f + 3) * 2 + 1];
#pragma unroll
    for (int m = 4; m >= 1; m >>= 1) {
      o0 += __shfl_xor(o0, m);
      o1 += __shfl_xor(o1, m);
    }
    if ((tid & 7) == 0) {
      float2 ov;
      ov.x = o0 + bc2[0];
      ov.y = o1 + bc2[1];
      *(float2*)(dout + (size_t)(node0 + nd) * 2) = ov;
    }
  }
}

extern "C" void kernel_launch(void* const* d_in, const int* in_sizes, int n_in,
                              void* d_out, int out_size, void* d_ws, size_t ws_size,
                              hipStream_t stream) {
  const float* x_ind = (const float*)d_in[0];
  const float* x_com = (const float*)d_in[1];
  const float* x_tru = (const float*)d_in[2];
  const int*   ei    = (const int*)d_in[3];
  const float* W_ind = (const float*)d_in[4];
  const float* b_ind = (const float*)d_in[5];
  const float* W_com = (const float*)d_in[6];
  const float* b_com = (const float*)d_in[7];
  const float* W_tru = (const float*)d_in[8];
  const float* b_tru = (const float*)d_in[9];
  const float* W1l = (const float*)d_in[10];
  const float* W1r = (const float*)d_in[11];
  const float* b1  = (const float*)d_in[12];
  const float* W2l = (const float*)d_in[13];
  const float* W2r = (const float*)d_in[14];
  const float* b2  = (const float*)d_in[15];
  const float* Wc1 = (const float*)d_in[16];
  const float* bc1 = (const float*)d_in[17];
  const float* Wc2 = (const float*)d_in[18];
  const float* bc2 = (const float*)d_in[19];

  const int* srcp = ei;           // edge_index[0]
  const int* dstp = ei + NEDGE;   // edge_index[1]

  // workspace layout (~125 MB; >=252 MB proven available)
  size_t fcount = (size_t)NTOT * HDIM;
  size_t pksz = (size_t)NCB * CAP;                        // sparse bucket regions
  unsigned* packed = (unsigned*)d_ws;                     // edge staging (21.6 MB)
  unsigned short* xh0 = (unsigned short*)(packed + pksz); // fp16 layer-0 features
  unsigned short* xh1 = xh0 + fcount;                     // fp16 layer-1 features
  int* eidx    = (int*)(xh1 + fcount);                    // sparse CSR storage (21.6 MB)
  int* nodeoff = eidx + pksz;
  int* deg     = nodeoff + NTOT;
  int* ccur    = deg + NTOT;
  // 16B-aligned weight-fragment area (4 matrices x 4096 halfs = 32 KB)
  unsigned short* wfrag = (unsigned short*)((((size_t)(ccur + NCB)) + 15) & ~(size_t)15);
  size_t needed = (size_t)((char*)(wfrag + 4 * 4096) - (char*)d_ws) + 64;
  if (ws_size < needed) return;  // would corrupt; fail visibly instead

  // prep: weight swizzle + ccur init + deg zero; gates the mega kernel (in-order)
  prep_weights_kernel<<<NBLK_PREP, 256, 0, stream>>>(W1l, W1r, W2l, W2r, wfrag, ccur, deg);

  // MEGA front: 3 encoders + coarse scatter (+deg atomics) co-dispatched
  mega_front_kernel<<<NBLK_MEGA, 256, 0, stream>>>(
      x_ind, W_ind, b_ind, x_com, W_com, b_com, x_tru, W_tru, b_tru,
      xh0, srcp, dstp, ccur, packed, deg);

  // per-bucket rank scatter -> node-grouped CSR (single pass; deg precomputed)
  sort_coarse_kernel<<<NCB, 1024, 0, stream>>>(packed, ccur, deg, eidx, nodeoff);

  // SAGE layer 1 fused: aggregate (uint4/8-lane) -> LDS -> MFMA -> fp16 xh1
  agg_combine_kernel<false><<<NTILES32, 256, 0, stream>>>(
      xh0, nodeoff, deg, eidx, wfrag, b1, xh1, nullptr, nullptr, nullptr, nullptr, nullptr);

  // SAGE layer 2 fused: aggregate -> LDS -> MFMA combine -> classifier -> d_out
  agg_combine_kernel<true><<<NTILES32, 256, 0, stream>>>(
      xh1, nodeoff, deg, eidx, wfrag + 2 * 4096, b2, nullptr, Wc1, bc1, Wc2, bc2,
      (float*)d_out);
}

// Round 11
// 466.447 us; speedup vs baseline: 1.3257x; 1.3257x over previous
//
#include <hip/hip_runtime.h>

#define N_IND 100000
#define N_COM 100000
#define N_TRU 100000
#define NTOT  300000
#define NEDGE 4800000
#define HDIM  64
#define CHUNK 8192
#define NCHUNKS 586   // ceil(NEDGE/CHUNK)
#define NCB 293   // ceil(NTOT/1024) coarse buckets of 1024 nodes
#define CAP 18432 // fixed bucket capacity = 16384 (mean) + 16 sigma (128)
#define PADW 33   // 32 cols + 1 pad (encoder epilogue)
#define NTILES32 9375 // NTOT / 32 exactly
#define NBLK_ENC1 391 // ceil(100000/256)
#define NBLK_ENC  1173
#define NBLK_MEGA 1759 // 1173 encoder blocks + 586 scatter blocks
#define SMEM_BYTES 37184 // max(encoder 33792, scatter 36368), 16-aligned

typedef float v4f __attribute__((ext_vector_type(4)));
typedef unsigned short v4u __attribute__((ext_vector_type(4)));
typedef unsigned short v8u __attribute__((ext_vector_type(8)));
typedef _Float16 v8h __attribute__((ext_vector_type(8)));

static __device__ __forceinline__ float elem4(const float4 v, int j) {
  return j == 0 ? v.x : j == 1 ? v.y : j == 2 ? v.z : v.w;
}

// fp32 <-> fp16 (RTN via v_cvt)
static __device__ __forceinline__ unsigned short f2h(float f) {
  _Float16 h = (_Float16)f;
  return __builtin_bit_cast(unsigned short, h);
}
static __device__ __forceinline__ float h2f(unsigned short u) {
  return (float)__builtin_bit_cast(_Float16, u);
}

// acc += (float)lo_half(pk); acc2 += (float)hi_half(pk) — one v_fma_mix_f32 each.
// Bitwise identical to v_cvt_f32_f16 + v_add_f32 (exact convert, x1.0 exact, one round).
static __device__ __forceinline__ void fmix2(float& alo, float& ahi, unsigned pk) {
  asm("v_fma_mix_f32 %0, %1, 1.0, %0 op_sel:[0,0,0] op_sel_hi:[1,0,0]"
      : "+v"(alo) : "v"(pk));
  asm("v_fma_mix_f32 %0, %1, 1.0, %0 op_sel:[1,0,0] op_sel_hi:[1,0,0]"
      : "+v"(ahi) : "v"(pk));
}

// Coalesced fp16 epilogue for encoder (256 rows, 2 stages of 32 cols).
static __device__ __forceinline__ void store_rows_f16(
    unsigned short* __restrict__ out, float* __restrict__ st, const float* acc,
    int node0, int rows, int tid, bool active) {
#pragma unroll
  for (int stage = 0; stage < 2; ++stage) {
    __syncthreads();
    if (active) {
#pragma unroll
      for (int j = 0; j < 32; ++j) st[tid * PADW + j] = acc[stage * 32 + j];
    }
    __syncthreads();
#pragma unroll
    for (int it = 0; it < 8; ++it) {
      int e = it * 256 + tid;
      int r = e >> 3;
      int c = (e & 7) * 4;
      if (r < rows) {
        v4u o;
        o.x = f2h(st[r * PADW + c + 0]);
        o.y = f2h(st[r * PADW + c + 1]);
        o.z = f2h(st[r * PADW + c + 2]);
        o.w = f2h(st[r * PADW + c + 3]);
        *(v4u*)(out + (size_t)(node0 + r) * HDIM + stage * 32 + c) = o;
      }
    }
  }
}

// ---------------- encoder body: xh[base+n] = fp16(x[n] @ W + b) ----------------
template <int K>
static __device__ void encode_body(
    const float* __restrict__ xin, const float* __restrict__ W,
    const float* __restrict__ b, unsigned short* __restrict__ xhout,
    int n, int base, int blk, float* st) {
  int tid = threadIdx.x;
  int node0 = blk * 256;
  int node = node0 + tid;
  bool active = node < n;
  int rows = min(256, n - node0);
  float acc[HDIM];
  if (active) {
    float4 row[K / 4];
    const float4* xv = (const float4*)(xin + (size_t)node * K);
#pragma unroll
    for (int i = 0; i < K / 4; ++i) row[i] = xv[i];
#pragma unroll
    for (int f = 0; f < HDIM; ++f) acc[f] = b[f];  // uniform -> s_load
#pragma unroll
    for (int k4 = 0; k4 < K / 4; ++k4) {
#pragma unroll
      for (int j = 0; j < 4; ++j) {
        float xs = elem4(row[k4], j);
        int k = k4 * 4 + j;
#pragma unroll
        for (int f = 0; f < HDIM; ++f) acc[f] += xs * W[k * HDIM + f];
      }
    }
  }
  store_rows_f16(xhout + (size_t)base * HDIM, st, acc, node0, rows, tid, active);
}

// ---------------- scatter body: LDS-staged local sort, coalesced run writes ----------
// CHUNK=8192 (long runs, no write amplification — round-9 lesson). bid[] array
// eliminated: phase D recovers bucket(i) from the inclusive scan sv via a forward
// cursor (<=293 LDS advances per thread). LDS 36.3 KB -> union 37.2 KB -> 4 blocks/CU.
// NO global deg atomics (round-9: 4.8M cross-XCD atomics cost ~150 MB coherence
// traffic). Output bit-identical to round-8 scatter.
static __device__ void scatter_body(
    const int* __restrict__ src, const int* __restrict__ dst,
    int* __restrict__ ccur, unsigned* __restrict__ packed, int e, int blk,
    char* smem) {
  int* h = (int*)smem;                       // NCB counts / rank counters
  int* gofs = h + NCB;                       // NCB global-offset deltas
  int* sv = gofs + NCB;                      // 512-wide scan buffer (persists)
  unsigned* vals = (unsigned*)(sv + 512);    // CHUNK sorted values
  int tid = threadIdx.x;
  int start = blk * CHUNK;
  int len = min(CHUNK, e - start);

  for (int i = tid; i < NCB; i += 256) h[i] = 0;
  __syncthreads();

  // Phase A: histogram; keep dst values in registers for phase C.
  int dreg[CHUNK / 256];
#pragma unroll
  for (int k = 0; k < CHUNK / 256; ++k) {
    int i = k * 256 + tid;
    dreg[k] = (i < len) ? dst[start + i] : -1;
    if (i < len) atomicAdd(&h[dreg[k] >> 10], 1);
  }
  __syncthreads();

  // Phase B: 512-wide Hillis-Steele scan (256 threads x 2 slots), reserve runs.
  sv[tid] = (tid < NCB) ? h[tid] : 0;
  sv[tid + 256] = (tid + 256 < NCB) ? h[tid + 256] : 0;
  __syncthreads();
  for (int o = 1; o < 512; o <<= 1) {
    int y0 = (tid >= o) ? sv[tid - o] : 0;
    int y1 = sv[tid + 256 - o];  // tid+256 >= o always (o <= 256)
    __syncthreads();
    sv[tid] += y0;
    sv[tid + 256] += y1;
    __syncthreads();
  }
  for (int b = tid; b < NCB; b += 256) {
    int c = h[b];
    int lo = (b == 0) ? 0 : sv[b - 1];
    int gb = (c > 0) ? atomicAdd(&ccur[b], c) : 0;  // reserve contiguous run
    gofs[b] = gb - lo;
    h[b] = lo;  // reuse as rank counter
  }
  __syncthreads();

  // Phase C: scatter into LDS in locally-sorted order (slot in [lofs[b], sv[b])).
#pragma unroll
  for (int k = 0; k < CHUNK / 256; ++k) {
    int i = k * 256 + tid;
    if (i < len) {
      int d = dreg[k];
      int s = src[start + i];
      int b = d >> 10;
      int slot = atomicAdd(&h[b], 1);
      vals[slot] = ((unsigned)s << 10) | (unsigned)(d & 1023);
    }
  }
  __syncthreads();

  // Phase D: coalesced sweep; bucket(i) = min b with sv[b] > i (forward cursor,
  // b only advances — ascending i per thread).
  int b = 0;
  for (int i = tid; i < len; i += 256) {
    while (sv[b] <= i) ++b;
    packed[gofs[b] + i] = vals[i];
  }
}

// ---------------- MEGA front: encoders + coarse scatter in ONE dispatch ----------------
// Blocks 0..1172: per-type encoders. Blocks 1173..1758: scatter chunks. LDS union
// 37.2 KB -> 4 blocks/CU target (round-8's 53.5 KB capped residency at 2 blocks/25%).
__global__ __launch_bounds__(256, 4) void mega_front_kernel(
    const float* __restrict__ x_ind, const float* __restrict__ W_ind, const float* __restrict__ b_ind,
    const float* __restrict__ x_com, const float* __restrict__ W_com, const float* __restrict__ b_com,
    const float* __restrict__ x_tru, const float* __restrict__ W_tru, const float* __restrict__ b_tru,
    unsigned short* __restrict__ xh0,
    const int* __restrict__ src, const int* __restrict__ dst,
    int* __restrict__ ccur, unsigned* __restrict__ packed) {
  __shared__ __align__(16) char smem[SMEM_BYTES];
  int bid = blockIdx.x;
  if (bid < NBLK_ENC1) {
    encode_body<32>(x_ind, W_ind, b_ind, xh0, N_IND, 0, bid, (float*)smem);
  } else if (bid < 2 * NBLK_ENC1) {
    encode_body<48>(x_com, W_com, b_com, xh0, N_COM, N_IND, bid - NBLK_ENC1, (float*)smem);
  } else if (bid < NBLK_ENC) {
    encode_body<24>(x_tru, W_tru, b_tru, xh0, N_TRU, N_IND + N_COM, bid - 2 * NBLK_ENC1,
                    (float*)smem);
  } else {
    scatter_body(src, dst, ccur, packed, NEDGE, bid - NBLK_ENC, smem);
  }
}

// ---------------- prep: weight swizzle + ccur init (parallel) ----------------
__global__ __launch_bounds__(256) void prep_weights_kernel(
    const float* __restrict__ W1l, const float* __restrict__ W1r,
    const float* __restrict__ W2l, const float* __restrict__ W2r,
    unsigned short* __restrict__ out, int* __restrict__ ccur) {
  int bid = blockIdx.x;
  int tid = threadIdx.x;
  if (bid == 64) {
    for (int b = tid; b < NCB; b += 256) ccur[b] = b * CAP;
    return;
  }
  int idx = bid * 256 + tid;   // 0..16383
  int m = idx >> 12;
  int id2 = idx & 4095;
  const float* W = (m == 0) ? W1l : (m == 1) ? W1r : (m == 2) ? W2l : W2r;
  int j = id2 & 7;
  int l = (id2 >> 3) & 63;
  int ts = id2 >> 9;
  int t = ts >> 1, s = ts & 1;
  int k = s * 32 + (l >> 4) * 8 + j;
  int n = t * 16 + (l & 15);
  out[m * 4096 + id2] = f2h(W[k * HDIM + n]);
}

// ---------------- per-coarse-bucket counting sort -> node-grouped CSR ----------------
// Round-8 proven two-pass version: 1024 threads/block, 293 blocks, bit-identical eidx.
__global__ __launch_bounds__(1024) void sort_coarse_kernel(
    const unsigned* __restrict__ packed, const int* __restrict__ ccur,
    int* __restrict__ eidx, int* __restrict__ nodeoff, int* __restrict__ deg) {
  __shared__ int cnts[1024];
  __shared__ int cur[1024];
  __shared__ int sv[1024];
  int cb = blockIdx.x;
  int tid = threadIdx.x;
  cnts[tid] = 0;
  __syncthreads();
  int base = cb * CAP;
  int cnt = ccur[cb] - base;
  for (int i = tid; i < cnt; i += 1024)
    atomicAdd(&cnts[packed[base + i] & 1023u], 1);
  __syncthreads();
  int c = cnts[tid];
  sv[tid] = c;
  __syncthreads();
  for (int o = 1; o < 1024; o <<= 1) {
    int y = (tid >= o) ? sv[tid - o] : 0;
    __syncthreads();
    sv[tid] += y;
    __syncthreads();
  }
  int ex = sv[tid] - c;   // exclusive prefix
  cur[tid] = ex;
  int node = (cb << 10) + tid;
  if (node < NTOT) { deg[node] = c; nodeoff[node] = base + ex; }
  __syncthreads();
  for (int i = tid; i < cnt; i += 1024) {
    unsigned pr = packed[base + i];
    int dl = (int)(pr & 1023u);
    int r = atomicAdd(&cur[dl], 1);
    eidx[base + r] = (int)(pr >> 10);  // 72 KB region exclusive to this block
  }
}

// ---------------- fused: aggregate -> LDS mean -> MFMA combine -> output ----------------
// Block = 256 threads = 32-node tile; 8 lanes/node x uint4 (16 B/lane, 128 B/row).
// At structural floor: FETCH 304 MB = compulsory 8-XCD table fetch; 2.85 TB/s = HBM
// random-128B service rate; occupancy/width levers exhausted (rounds 4,7).
#define SMPAD 72
template <bool LAYER2>
__global__ __launch_bounds__(256, 7) void agg_combine_kernel(
    const unsigned short* __restrict__ xh, const int* __restrict__ off,
    const int* __restrict__ deg, const int* __restrict__ eidx,
    const unsigned short* __restrict__ wfrag,  // this layer's 2 matrices
    const float* __restrict__ bb,
    unsigned short* __restrict__ outh,         // layer1 output (fp16)
    const float* __restrict__ Wc1, const float* __restrict__ bc1,
    const float* __restrict__ Wc2, const float* __restrict__ bc2,
    float* __restrict__ dout) {                // layer2 classifier output
  __shared__ unsigned short smean[32 * SMPAD];
  __shared__ float st[32 * 68 + 8];
  __shared__ float sW1[LAYER2 ? 2048 : 8];
  int tid = threadIdx.x;
  int node0 = blockIdx.x * 32;

  // ---- phase 1: aggregate; 8 lanes/node, uint4 loads (16 B/lane, 128 B/row) ----
  {
    int nit = tid >> 3;        // node in tile (0..31)
    int lane8 = tid & 7;
    int node = node0 + nit;
    int start = off[node];
    int d = deg[node];
    const char* xb = (const char*)xh;
    unsigned rofs = (unsigned)(lane8 << 4);  // byte offset of this lane in a 128 B row
    // 2 accumulation banks of 8 features; edge e -> bank e&1
    float acc[16];
#pragma unroll
    for (int j = 0; j < 16; ++j) acc[j] = 0.f;
    int i = 0;
    for (; i + 8 <= d; i += 8) {
      const int* ep = eidx + start + i;
      int s[8];
#pragma unroll
      for (int k = 0; k < 8; ++k) s[k] = ep[k];
      uint4 v[8];
#pragma unroll
      for (int k = 0; k < 8; ++k)
        v[k] = *(const uint4*)(xb + ((((unsigned)s[k]) << 7) + rofs));
#pragma unroll
      for (int k = 0; k < 8; ++k) {
        float* a = &acc[(k & 1) * 8];
        fmix2(a[0], a[1], v[k].x);
        fmix2(a[2], a[3], v[k].y);
        fmix2(a[4], a[5], v[k].z);
        fmix2(a[6], a[7], v[k].w);
      }
    }
    if (i + 4 <= d) {
      const int* ep = eidx + start + i;
      int s[4];
#pragma unroll
      for (int k = 0; k < 4; ++k) s[k] = ep[k];
      uint4 v[4];
#pragma unroll
      for (int k = 0; k < 4; ++k)
        v[k] = *(const uint4*)(xb + ((((unsigned)s[k]) << 7) + rofs));
#pragma unroll
      for (int k = 0; k < 4; ++k) {
        float* a = &acc[(k & 1) * 8];
        fmix2(a[0], a[1], v[k].x);
        fmix2(a[2], a[3], v[k].y);
        fmix2(a[4], a[5], v[k].z);
        fmix2(a[6], a[7], v[k].w);
      }
      i += 4;
    }
    for (; i < d; ++i) {
      int s = eidx[start + i];
      uint4 v = *(const uint4*)(xb + ((((unsigned)s) << 7) + rofs));
      fmix2(acc[0], acc[1], v.x);
      fmix2(acc[2], acc[3], v.y);
      fmix2(acc[4], acc[5], v.z);
      fmix2(acc[6], acc[7], v.w);
    }
    float inv = 1.0f / (float)(d > 0 ? d : 1);
    v8u o;
#pragma unroll
    for (int j = 0; j < 8; ++j) o[j] = f2h((acc[j] + acc[8 + j]) * inv);
    *(v8u*)&smean[nit * SMPAD + lane8 * 8] = o;  // 16 B store, row base 144 B (16-aligned)
  }
  if (LAYER2) {
    for (int i = tid; i < 2048; i += 256) sW1[i] = Wc1[i];
  }
  __syncthreads();

  // ---- phase 2: combine; 8 tasks (rt 0..1 x cb 0..3), wave wid does tasks wid*2+{0,1} ----
  int wid = tid >> 6;
  int lane = tid & 63;
  int mlo = lane & 15;
  int quad = lane >> 4;
  {
    const v8h* wf = (const v8h*)wfrag;
#pragma unroll
    for (int p = 0; p < 2; ++p) {
      int task = wid * 2 + p;
      int rt = task >> 2, cb = task & 3;
      v8h BL0 = wf[(cb * 2 + 0) * 64 + lane];
      v8h BL1 = wf[(cb * 2 + 1) * 64 + lane];
      v8h BR0 = wf[512 + (cb * 2 + 0) * 64 + lane];
      v8h BR1 = wf[512 + (cb * 2 + 1) * 64 + lane];
      float bias = bb[cb * 16 + mlo];
      int arow = rt * 16 + mlo;
      v8h Am0 = *(const v8h*)&smean[arow * SMPAD + quad * 8];
      v8h Am1 = *(const v8h*)&smean[arow * SMPAD + quad * 8 + 32];
      const _Float16* xrow =
          (const _Float16*)xh + (size_t)(node0 + arow) * HDIM + quad * 8;
      v8h Ax0 = *(const v8h*)(xrow);
      v8h Ax1 = *(const v8h*)(xrow + 32);
      v4f acc = {bias, bias, bias, bias};
      acc = __builtin_amdgcn_mfma_f32_16x16x32_f16(Am0, BL0, acc, 0, 0, 0);
      acc = __builtin_amdgcn_mfma_f32_16x16x32_f16(Am1, BL1, acc, 0, 0, 0);
      acc = __builtin_amdgcn_mfma_f32_16x16x32_f16(Ax0, BR0, acc, 0, 0, 0);
      acc = __builtin_amdgcn_mfma_f32_16x16x32_f16(Ax1, BR1, acc, 0, 0, 0);
#pragma unroll
      for (int r = 0; r < 4; ++r)
        st[(rt * 16 + quad * 4 + r) * 68 + cb * 16 + mlo] = fmaxf(acc[r], 0.f);
    }
  }
  __syncthreads();

  // ---- phase 3: output ----
  if (!LAYER2) {
    // coalesced fp16 store of the 32x64 tile: row = tid>>3, 8 cols per thread
    int r = tid >> 3;
    int c = (tid & 7) * 8;
    const float* ap = &st[r * 68 + c];
    v8u o;
#pragma unroll
    for (int j = 0; j < 8; ++j) o[j] = f2h(ap[j]);
    *(v8u*)(outh + (size_t)(node0 + r) * HDIM + c) = o;
  } else {
    // classifier: 8 threads/node, 4 hidden units each, shfl-tree reduce over 8 lanes
    int nd = tid >> 3;
    int f = (tid & 7) * 4;
    float h0 = bc1[f], h1 = bc1[f + 1], h2 = bc1[f + 2], h3 = bc1[f + 3];
    const float* xr = &st[nd * 68];
#pragma unroll
    for (int k = 0; k < 64; ++k) {
      float xv = xr[k];
      h0 += xv * sW1[k * 32 + f + 0];
      h1 += xv * sW1[k * 32 + f + 1];
      h2 += xv * sW1[k * 32 + f + 2];
      h3 += xv * sW1[k * 32 + f + 3];
    }
    h0 = fmaxf(h0, 0.f); h1 = fmaxf(h1, 0.f);
    h2 = fmaxf(h2, 0.f); h3 = fmaxf(h3, 0.f);
    float o0 = h0 * Wc2[f * 2 + 0] + h1 * Wc2[(f + 1) * 2 + 0] +
               h2 * Wc2[(f + 2) * 2 + 0] + h3 * Wc2[(f + 3) * 2 + 0];
    float o1 = h0 * Wc2[f * 2 + 1] + h1 * Wc2[(f + 1) * 2 + 1] +
               h2 * Wc2[(f + 2) * 2 + 1] + h3 * Wc2[(f + 3) * 2 + 1];
#pragma unroll
    for (int m = 4; m >= 1; m >>= 1) {
      o0 += __shfl_xor(o0, m);
      o1 += __shfl_xor(o1, m);
    }
    if ((tid & 7) == 0) {
      float2 ov;
      ov.x = o0 + bc2[0];
      ov.y = o1 + bc2[1];
      *(float2*)(dout + (size_t)(node0 + nd) * 2) = ov;
    }
  }
}

extern "C" void kernel_launch(void* const* d_in, const int* in_sizes, int n_in,
                              void* d_out, int out_size, void* d_ws, size_t ws_size,
                              hipStream_t stream) {
  const float* x_ind = (const float*)d_in[0];
  const float* x_com = (const float*)d_in[1];
  const float* x_tru = (const float*)d_in[2];
  const int*   ei    = (const int*)d_in[3];
  const float* W_ind = (const float*)d_in[4];
  const float* b_ind = (const float*)d_in[5];
  const float* W_com = (const float*)d_in[6];
  const float* b_com = (const float*)d_in[7];
  const float* W_tru = (const float*)d_in[8];
  const float* b_tru = (const float*)d_in[9];
  const float* W1l = (const float*)d_in[10];
  const float* W1r = (const float*)d_in[11];
  const float* b1  = (const float*)d_in[12];
  const float* W2l = (const float*)d_in[13];
  const float* W2r = (const float*)d_in[14];
  const float* b2  = (const float*)d_in[15];
  const float* Wc1 = (const float*)d_in[16];
  const float* bc1 = (const float*)d_in[17];
  const float* Wc2 = (const float*)d_in[18];
  const float* bc2 = (const float*)d_in[19];

  const int* srcp = ei;           // edge_index[0]
  const int* dstp = ei + NEDGE;   // edge_index[1]

  // workspace layout (~125 MB; >=252 MB proven available)
  size_t fcount = (size_t)NTOT * HDIM;
  size_t pksz = (size_t)NCB * CAP;                        // sparse bucket regions
  unsigned* packed = (unsigned*)d_ws;                     // edge staging (21.6 MB)
  unsigned short* xh0 = (unsigned short*)(packed + pksz); // fp16 layer-0 features
  unsigned short* xh1 = xh0 + fcount;                     // fp16 layer-1 features
  int* eidx    = (int*)(xh1 + fcount);                    // sparse CSR storage (21.6 MB)
  int* nodeoff = eidx + pksz;
  int* deg     = nodeoff + NTOT;
  int* ccur    = deg + NTOT;
  // 16B-aligned weight-fragment area (4 matrices x 4096 halfs = 32 KB)
  unsigned short* wfrag = (unsigned short*)((((size_t)(ccur + NCB)) + 15) & ~(size_t)15);
  size_t needed = (size_t)((char*)(wfrag + 4 * 4096) - (char*)d_ws) + 64;
  if (ws_size < needed) return;  // would corrupt; fail visibly instead

  // prep: weight swizzle + ccur init; gates the mega kernel (in-order)
  prep_weights_kernel<<<65, 256, 0, stream>>>(W1l, W1r, W2l, W2r, wfrag, ccur);

  // MEGA front: 3 encoders + coarse scatter co-dispatched (independent block roles)
  mega_front_kernel<<<NBLK_MEGA, 256, 0, stream>>>(
      x_ind, W_ind, b_ind, x_com, W_com, b_com, x_tru, W_tru, b_tru,
      xh0, srcp, dstp, ccur, packed);

  // per-bucket counting sort -> node-grouped CSR
  sort_coarse_kernel<<<NCB, 1024, 0, stream>>>(packed, ccur, eidx, nodeoff, deg);

  // SAGE layer 1 fused: aggregate (uint4/8-lane) -> LDS -> MFMA -> fp16 xh1
  agg_combine_kernel<false><<<NTILES32, 256, 0, stream>>>(
      xh0, nodeoff, deg, eidx, wfrag, b1, xh1, nullptr, nullptr, nullptr, nullptr, nullptr);

  // SAGE layer 2 fused: aggregate -> LDS -> MFMA combine -> classifier -> d_out
  agg_combine_kernel<true><<<NTILES32, 256, 0, stream>>>(
      xh1, nodeoff, deg, eidx, wfrag + 2 * 4096, b2, nullptr, Wc1, bc1, Wc2, bc2,
      (float*)d_out);
}